// Round 9
// baseline (926.947 us; speedup 1.0000x reference)
//
#include <hip/hip_runtime.h>
#include <hip/hip_fp16.h>
#include <cstdint>
#include <cstddef>

#define NEG 0.2f
#define TILE 4096   // edges per partition tile

// ---------------- CSR build: hist + scan ----------------

__global__ __launch_bounds__(256) void hist_k(const int* __restrict__ ei, int* __restrict__ cnt, int E) {
    int i = blockIdx.x * 256 + threadIdx.x;
    if (i < E) atomicAdd(&cnt[__builtin_nontemporal_load(ei + E + i)], 1);
}

__global__ __launch_bounds__(256) void scan1_k(const int* __restrict__ cnt, int* __restrict__ rp,
                                               int* __restrict__ bs, int N) {
    __shared__ int sm[256];
    int t = threadIdx.x, i = blockIdx.x * 256 + t;
    int v = (i < N) ? cnt[i] : 0;
    sm[t] = v; __syncthreads();
    for (int off = 1; off < 256; off <<= 1) {
        int u = (t >= off) ? sm[t - off] : 0;
        __syncthreads();
        sm[t] += u;
        __syncthreads();
    }
    if (i < N) rp[i] = sm[t] - v;          // exclusive within block
    if (t == 255) bs[blockIdx.x] = sm[255];
}

__global__ __launch_bounds__(1024) void scan2_k(int* __restrict__ bs, int nb) {
    __shared__ int sm[1024];
    int t = threadIdx.x;
    int v = (t < nb) ? bs[t] : 0;
    sm[t] = v; __syncthreads();
    for (int off = 1; off < 1024; off <<= 1) {
        int u = (t >= off) ? sm[t - off] : 0;
        __syncthreads();
        sm[t] += u;
        __syncthreads();
    }
    if (t < nb) bs[t] = sm[t] - v;         // exclusive block offsets
}

__global__ __launch_bounds__(256) void scan3_k(int* __restrict__ rp, const int* __restrict__ bs, int N) {
    int i = blockIdx.x * 256 + threadIdx.x;
    if (i < N) rp[i] += bs[blockIdx.x];
}

__global__ __launch_bounds__(256) void initA_k(const int* __restrict__ rp, int* __restrict__ curA, int nbk) {
    int b = threadIdx.x;
    if (b < nbk) curA[b] = rp[b << 9];
}

// ---------------- Degree-sorted node permutation (256-bin counting sort) ----------------

__global__ __launch_bounds__(256) void dhist_k(const int* __restrict__ cnt, int* __restrict__ dbins, int N) {
    int i = blockIdx.x * 256 + threadIdx.x;
    if (i < N) atomicAdd(&dbins[min(cnt[i], 255)], 1);
}

__global__ __launch_bounds__(256) void dscan_k(const int* __restrict__ dbins, int* __restrict__ dcur) {
    __shared__ int sm[256];
    int t = threadIdx.x;
    int v = dbins[t];
    sm[t] = v; __syncthreads();
    for (int off = 1; off < 256; off <<= 1) {
        int u = (t >= off) ? sm[t - off] : 0;
        __syncthreads();
        sm[t] += u;
        __syncthreads();
    }
    dcur[t] = sm[t] - v;   // exclusive scan -> running cursor
}

__global__ __launch_bounds__(256) void dperm_k(const int* __restrict__ cnt, int* __restrict__ dcur,
                                               int* __restrict__ perm, int N) {
    int i = blockIdx.x * 256 + threadIdx.x;
    if (i < N) {
        int b = min(cnt[i], 255);
        int pos = atomicAdd(&dcur[b], 1);
        perm[pos] = i;
    }
}

// ---------------- Phase A: LDS-staged partition of edges into 512-node buckets ----------------

__global__ __launch_bounds__(256) void partA_k(const int* __restrict__ ei, int* __restrict__ curA,
                                               uint2* __restrict__ pairs, int E, int nbk) {
    __shared__ int scnt[256];
    __shared__ int sc[256];
    __shared__ int sbase[256];
    __shared__ int gbase[256];
    __shared__ int cur2[256];
    __shared__ int ssrc[TILE];
    __shared__ int sdst[TILE];
    int t = threadIdx.x;
    int ntiles = (E + TILE - 1) / TILE;
    for (int tile = blockIdx.x; tile < ntiles; tile += gridDim.x) {
        int base = tile * TILE;
        int cntE = min(TILE, E - base);
        scnt[t] = 0;
        __syncthreads();
        int mys[16], myd[16];
        #pragma unroll
        for (int j = 0; j < 16; j++) {
            int i = base + t + 256 * j;
            int s = 0, d = -1;
            if (i < E) {
                s = __builtin_nontemporal_load(ei + i);
                d = __builtin_nontemporal_load(ei + E + i);
            }
            mys[j] = s; myd[j] = d;
            if (d >= 0) atomicAdd(&scnt[d >> 9], 1);
        }
        __syncthreads();
        sc[t] = scnt[t];
        __syncthreads();
        for (int off = 1; off < 256; off <<= 1) {
            int u = (t >= off) ? sc[t - off] : 0;
            __syncthreads();
            sc[t] += u;
            __syncthreads();
        }
        int myb = sc[t] - scnt[t];
        sbase[t] = myb;
        cur2[t] = myb;
        if (t < nbk && scnt[t] > 0) gbase[t] = atomicAdd(&curA[t], scnt[t]);
        __syncthreads();
        #pragma unroll
        for (int j = 0; j < 16; j++) {
            int d = myd[j];
            if (d >= 0) {
                int b = d >> 9;
                int pos = atomicAdd(&cur2[b], 1);
                ssrc[pos] = mys[j];
                sdst[pos] = d;
            }
        }
        __syncthreads();
        for (int i = t; i < cntE; i += 256) {
            int d = sdst[i];
            int b = d >> 9;
            int addr = gbase[b] + (i - sbase[b]);
            pairs[addr] = make_uint2((unsigned)ssrc[i], (unsigned)d);
        }
        __syncthreads();
    }
}

// ---------------- Phase B: per-bucket scatter to per-node CSR positions ----------------

__global__ __launch_bounds__(256) void partB_pairs_k(const uint2* __restrict__ pin, const int* __restrict__ rp,
                                                     int* __restrict__ srcout, int E, int N) {
    __shared__ int cur[512];
    int b = blockIdx.x;
    int t = threadIdx.x;
    int d0 = b << 9;
    cur[t] = 0; cur[t + 256] = 0;
    __syncthreads();
    int hi = d0 + 512;
    int ebase = rp[d0];
    int eend = (hi >= N) ? E : rp[hi];
    for (int j = ebase + t; j < eend; j += 256) {
        uint2 p = pin[j];
        int d = (int)p.y;
        int pos = rp[d] + atomicAdd(&cur[d - d0], 1);
        srcout[pos] = (int)p.x;
    }
}

// ---------------- Layer 1 GEMM: h1 = x @ W1 (fp16 out), register-tiled ----------------

__global__ __launch_bounds__(256) void gemm1_k(const float* __restrict__ x, const float* __restrict__ W,
                                               const float* __restrict__ a_src, const float* __restrict__ a_dst,
                                               __half* __restrict__ h, float* __restrict__ alsrc,
                                               float* __restrict__ aldst, int N) {
    __shared__ float Bs[128 * 64];
    __shared__ float xs[64][68];
    int t = threadIdx.x;
    for (int i = t; i < 128 * 64 / 4; i += 256)
        ((float4*)Bs)[i] = ((const float4*)W)[i];
    int ct = t & 15, rt = t >> 4;
    int head = ct >> 2, cq = ct & 3;
    float asv[4], adv[4];
    #pragma unroll
    for (int j = 0; j < 4; j++) {
        asv[j] = a_src[head * 16 + 4 * cq + j];
        adv[j] = a_dst[head * 16 + 4 * cq + j];
    }
    int ntiles = (N + 63) >> 6;
    for (int tile = blockIdx.x; tile < ntiles; tile += gridDim.x) {
        int r0 = tile << 6;
        float acc[4][4];
        #pragma unroll
        for (int i = 0; i < 4; i++)
            #pragma unroll
            for (int j = 0; j < 4; j++) acc[i][j] = 0.f;
        for (int kc = 0; kc < 128; kc += 64) {
            __syncthreads();
            int srow = t >> 4, sf4 = t & 15;
            #pragma unroll
            for (int p = 0; p < 4; p++) {
                int r = r0 + srow + 16 * p;
                float4 v = make_float4(0.f, 0.f, 0.f, 0.f);
                if (r < N) v = *(const float4*)(x + (size_t)r * 128 + kc + 4 * sf4);
                *(float4*)&xs[srow + 16 * p][4 * sf4] = v;
            }
            __syncthreads();
            #pragma unroll 4
            for (int k = 0; k < 64; k++) {
                float4 bv = *(float4*)&Bs[(kc + k) * 64 + 4 * ct];
                #pragma unroll
                for (int i = 0; i < 4; i++) {
                    float xv = xs[4 * rt + i][k];
                    acc[i][0] = fmaf(xv, bv.x, acc[i][0]);
                    acc[i][1] = fmaf(xv, bv.y, acc[i][1]);
                    acc[i][2] = fmaf(xv, bv.z, acc[i][2]);
                    acc[i][3] = fmaf(xv, bv.w, acc[i][3]);
                }
            }
        }
        #pragma unroll
        for (int i = 0; i < 4; i++) {
            int r = r0 + 4 * rt + i;
            float ps = 0.f, pd = 0.f;
            #pragma unroll
            for (int j = 0; j < 4; j++) {
                ps = fmaf(acc[i][j], asv[j], ps);
                pd = fmaf(acc[i][j], adv[j], pd);
            }
            ps += __shfl_xor(ps, 1); ps += __shfl_xor(ps, 2);
            pd += __shfl_xor(pd, 1); pd += __shfl_xor(pd, 2);
            if (r < N) {
                __half2 h0 = __floats2half2_rn(acc[i][0], acc[i][1]);
                __half2 h1 = __floats2half2_rn(acc[i][2], acc[i][3]);
                *(__half2*)(h + (size_t)r * 64 + 4 * ct) = h0;
                *(__half2*)(h + (size_t)r * 64 + 4 * ct + 2) = h1;
                if (cq == 0) { alsrc[r * 4 + head] = ps; aldst[r * 4 + head] = pd; }
            }
        }
    }
}

// ---------------- Layer 1 node aggregation: quarter-wave per node, degree-sorted ----------------

__global__ __launch_bounds__(256) void node1_k(const __half* __restrict__ h, const int* __restrict__ srccol,
                                               const int* __restrict__ perm,
                                               const float* __restrict__ alsrc, const float* __restrict__ aldst,
                                               const int* __restrict__ rp, const int* __restrict__ cnt,
                                               const float* __restrict__ bias, __half* __restrict__ out, int N) {
    int t = threadIdx.x;
    int idx = (blockIdx.x * 256 + t) >> 4;
    if (idx >= N) return;
    int d = perm[idx];
    int c = t & 15;
    int hc = c >> 2;
    const __half2* hb = (const __half2*)h;
    unsigned co = 2u * c;
    float ad = aldst[d * 4 + hc];
    float e = alsrc[d * 4 + hc] + ad;
    float w = __expf(e > 0.f ? e : NEG * e);
    float den = w;
    __half2 wp = __float2half2_rn(w);
    uint2 u = *(const uint2*)(hb + ((unsigned)d << 5) + co);
    __half2 acc0 = __hmul2(wp, *(__half2*)&u.x);
    __half2 acc1 = __hmul2(wp, *(__half2*)&u.y);
    int start = rp[d], deg = cnt[d];
    int i = 0;
    for (; i + 1 < deg; i += 2) {
        int s0 = srccol[start + i];
        int s1 = srccol[start + i + 1];
        uint2 u0 = *(const uint2*)(hb + ((unsigned)s0 << 5) + co);
        uint2 u1 = *(const uint2*)(hb + ((unsigned)s1 << 5) + co);
        float e0 = alsrc[s0 * 4 + hc] + ad;
        float e1 = alsrc[s1 * 4 + hc] + ad;
        float w0 = __expf(e0 > 0.f ? e0 : NEG * e0);
        float w1 = __expf(e1 > 0.f ? e1 : NEG * e1);
        den += w0 + w1;
        __half2 wp0 = __float2half2_rn(w0), wp1 = __float2half2_rn(w1);
        acc0 = __hfma2(wp0, *(__half2*)&u0.x, acc0);
        acc1 = __hfma2(wp0, *(__half2*)&u0.y, acc1);
        acc0 = __hfma2(wp1, *(__half2*)&u1.x, acc0);
        acc1 = __hfma2(wp1, *(__half2*)&u1.y, acc1);
    }
    if (i < deg) {
        int s = srccol[start + i];
        uint2 us = *(const uint2*)(hb + ((unsigned)s << 5) + co);
        float es = alsrc[s * 4 + hc] + ad;
        float ws = __expf(es > 0.f ? es : NEG * es);
        den += ws;
        __half2 wps = __float2half2_rn(ws);
        acc0 = __hfma2(wps, *(__half2*)&us.x, acc0);
        acc1 = __hfma2(wps, *(__half2*)&us.y, acc1);
    }
    float inv = 1.f / den;
    float2 f0 = __half22float2(acc0), f1 = __half22float2(acc1);
    float4 b = *(const float4*)(bias + 4 * c);
    __half2 o0 = __floats2half2_rn(f0.x * inv + b.x, f0.y * inv + b.y);
    __half2 o1 = __floats2half2_rn(f1.x * inv + b.z, f1.y * inv + b.w);
    uint2 o; o.x = *(unsigned*)&o0; o.y = *(unsigned*)&o1;
    *(uint2*)(out + (size_t)d * 64 + 4 * c) = o;
}

// ---------------- Layer 2 GEMM: h2 = h1o(fp16) @ W2 (fp16 out), register-tiled ----------------

__global__ __launch_bounds__(256) void gemm2_k(const __half* __restrict__ xh, const float* __restrict__ W,
                                               const float* __restrict__ a_src, const float* __restrict__ a_dst,
                                               __half* __restrict__ h, float* __restrict__ alsrc,
                                               float* __restrict__ aldst, int N) {
    __shared__ float Bs[64 * 128];
    __shared__ float xs[64][68];
    int t = threadIdx.x;
    for (int i = t; i < 64 * 128 / 4; i += 256)
        ((float4*)Bs)[i] = ((const float4*)W)[i];
    int ct = t & 15, rt = t >> 4;
    int hA = ct >> 3, cq = ct & 7;
    float asA[4], adA[4], asB[4], adB[4];
    #pragma unroll
    for (int j = 0; j < 4; j++) {
        asA[j] = a_src[hA * 32 + 4 * cq + j];
        adA[j] = a_dst[hA * 32 + 4 * cq + j];
        asB[j] = a_src[(2 + hA) * 32 + 4 * cq + j];
        adB[j] = a_dst[(2 + hA) * 32 + 4 * cq + j];
    }
    int ntiles = (N + 63) >> 6;
    for (int tile = blockIdx.x; tile < ntiles; tile += gridDim.x) {
        int r0 = tile << 6;
        float accA[4][4], accB[4][4];
        #pragma unroll
        for (int i = 0; i < 4; i++)
            #pragma unroll
            for (int j = 0; j < 4; j++) { accA[i][j] = 0.f; accB[i][j] = 0.f; }
        __syncthreads();
        int srow = t >> 3, su = t & 7;
        #pragma unroll
        for (int p = 0; p < 2; p++) {
            int r = r0 + srow + 32 * p;
            float2 g0 = make_float2(0.f, 0.f), g1 = g0, g2 = g0, g3 = g0;
            if (r < N) {
                uint4 u = *(const uint4*)(xh + (size_t)r * 64 + 8 * su);
                const __half2* hp = (const __half2*)&u;
                g0 = __half22float2(hp[0]); g1 = __half22float2(hp[1]);
                g2 = __half22float2(hp[2]); g3 = __half22float2(hp[3]);
            }
            *(float4*)&xs[srow + 32 * p][8 * su] = make_float4(g0.x, g0.y, g1.x, g1.y);
            *(float4*)&xs[srow + 32 * p][8 * su + 4] = make_float4(g2.x, g2.y, g3.x, g3.y);
        }
        __syncthreads();
        #pragma unroll 4
        for (int k = 0; k < 64; k++) {
            float4 bA = *(float4*)&Bs[k * 128 + 4 * ct];
            float4 bB = *(float4*)&Bs[k * 128 + 64 + 4 * ct];
            #pragma unroll
            for (int i = 0; i < 4; i++) {
                float xv = xs[4 * rt + i][k];
                accA[i][0] = fmaf(xv, bA.x, accA[i][0]);
                accA[i][1] = fmaf(xv, bA.y, accA[i][1]);
                accA[i][2] = fmaf(xv, bA.z, accA[i][2]);
                accA[i][3] = fmaf(xv, bA.w, accA[i][3]);
                accB[i][0] = fmaf(xv, bB.x, accB[i][0]);
                accB[i][1] = fmaf(xv, bB.y, accB[i][1]);
                accB[i][2] = fmaf(xv, bB.z, accB[i][2]);
                accB[i][3] = fmaf(xv, bB.w, accB[i][3]);
            }
        }
        #pragma unroll
        for (int i = 0; i < 4; i++) {
            int r = r0 + 4 * rt + i;
            float psA = 0.f, pdA = 0.f, psB = 0.f, pdB = 0.f;
            #pragma unroll
            for (int j = 0; j < 4; j++) {
                psA = fmaf(accA[i][j], asA[j], psA);
                pdA = fmaf(accA[i][j], adA[j], pdA);
                psB = fmaf(accB[i][j], asB[j], psB);
                pdB = fmaf(accB[i][j], adB[j], pdB);
            }
            #pragma unroll
            for (int off = 1; off <= 4; off <<= 1) {
                psA += __shfl_xor(psA, off); pdA += __shfl_xor(pdA, off);
                psB += __shfl_xor(psB, off); pdB += __shfl_xor(pdB, off);
            }
            if (r < N) {
                __half2 hA0 = __floats2half2_rn(accA[i][0], accA[i][1]);
                __half2 hA1 = __floats2half2_rn(accA[i][2], accA[i][3]);
                __half2 hB0 = __floats2half2_rn(accB[i][0], accB[i][1]);
                __half2 hB1 = __floats2half2_rn(accB[i][2], accB[i][3]);
                *(__half2*)(h + (size_t)r * 128 + 4 * ct) = hA0;
                *(__half2*)(h + (size_t)r * 128 + 4 * ct + 2) = hA1;
                *(__half2*)(h + (size_t)r * 128 + 64 + 4 * ct) = hB0;
                *(__half2*)(h + (size_t)r * 128 + 64 + 4 * ct + 2) = hB1;
                if (cq == 0) {
                    alsrc[r * 4 + hA] = psA;     alsrc[r * 4 + 2 + hA] = psB;
                    aldst[r * 4 + hA] = pdA;     aldst[r * 4 + 2 + hA] = pdB;
                }
            }
        }
    }
}

// ---------------- Layer 2 node aggregation: quarter-wave per node, degree-sorted + epilogue ----------------

__global__ __launch_bounds__(256) void node2_k(const __half* __restrict__ h, const int* __restrict__ srccol,
                                               const int* __restrict__ perm,
                                               const float* __restrict__ alsrc, const float* __restrict__ aldst,
                                               const int* __restrict__ rp, const int* __restrict__ cnt,
                                               const float* __restrict__ bias, float* __restrict__ out, int N) {
    int t = threadIdx.x;
    int idx = (blockIdx.x * 256 + t) >> 4;
    if (idx >= N) return;
    int d = perm[idx];
    int c = t & 15;
    int hc = c >> 2, jc = c & 3;
    const __half2* hb = (const __half2*)h;
    unsigned co = 4u * c;
    float ad = aldst[d * 4 + hc];
    float e = alsrc[d * 4 + hc] + ad;
    float w = __expf(e > 0.f ? e : NEG * e);
    float den = w;
    __half2 wp = __float2half2_rn(w);
    uint4 u = *(const uint4*)(hb + ((unsigned)d << 6) + co);
    const __half2* hp = (const __half2*)&u;
    __half2 acc[4];
    #pragma unroll
    for (int j = 0; j < 4; j++) acc[j] = __hmul2(wp, hp[j]);
    int start = rp[d], deg = cnt[d];
    int i = 0;
    for (; i + 1 < deg; i += 2) {
        int s0 = srccol[start + i];
        int s1 = srccol[start + i + 1];
        uint4 u0 = *(const uint4*)(hb + ((unsigned)s0 << 6) + co);
        uint4 u1 = *(const uint4*)(hb + ((unsigned)s1 << 6) + co);
        float e0 = alsrc[s0 * 4 + hc] + ad;
        float e1 = alsrc[s1 * 4 + hc] + ad;
        float w0 = __expf(e0 > 0.f ? e0 : NEG * e0);
        float w1 = __expf(e1 > 0.f ? e1 : NEG * e1);
        den += w0 + w1;
        __half2 wp0 = __float2half2_rn(w0), wp1 = __float2half2_rn(w1);
        const __half2* hp0 = (const __half2*)&u0;
        const __half2* hp1 = (const __half2*)&u1;
        #pragma unroll
        for (int j = 0; j < 4; j++) acc[j] = __hfma2(wp0, hp0[j], acc[j]);
        #pragma unroll
        for (int j = 0; j < 4; j++) acc[j] = __hfma2(wp1, hp1[j], acc[j]);
    }
    if (i < deg) {
        int s = srccol[start + i];
        uint4 us = *(const uint4*)(hb + ((unsigned)s << 6) + co);
        float es = alsrc[s * 4 + hc] + ad;
        float ws = __expf(es > 0.f ? es : NEG * es);
        den += ws;
        __half2 wps = __float2half2_rn(ws);
        const __half2* hps = (const __half2*)&us;
        #pragma unroll
        for (int j = 0; j < 4; j++) acc[j] = __hfma2(wps, hps[j], acc[j]);
    }
    float inv = 1.f / den;
    float v[8];
    #pragma unroll
    for (int j = 0; j < 4; j++) {
        float2 f = __half22float2(acc[j]);
        v[2 * j] = f.x * inv; v[2 * j + 1] = f.y * inv;
    }
    // head-mean: sum across lanes with same jc (lane bits 4 and 8)
    #pragma unroll
    for (int off = 4; off <= 8; off <<= 1) {
        #pragma unroll
        for (int j = 0; j < 8; j++) v[j] += __shfl_xor(v[j], off);
    }
    float ev[8];
    #pragma unroll
    for (int j = 0; j < 8; j++) {
        float val = 0.25f * v[j] + bias[8 * jc + j];
        ev[j] = val > 0.f ? val : __expf(val) - 1.f;
    }
    float mx = ev[0];
    #pragma unroll
    for (int j = 1; j < 8; j++) mx = fmaxf(mx, ev[j]);
    #pragma unroll
    for (int off = 1; off <= 2; off <<= 1) mx = fmaxf(mx, __shfl_xor(mx, off));
    float sum = 0.f;
    #pragma unroll
    for (int j = 0; j < 8; j++) sum += __expf(ev[j] - mx);
    #pragma unroll
    for (int off = 1; off <= 2; off <<= 1) sum += __shfl_xor(sum, off);
    float ls = mx + __logf(sum);
    if (c < 4) {
        float4 o0, o1;
        o0.x = ev[0] - ls; o0.y = ev[1] - ls; o0.z = ev[2] - ls; o0.w = ev[3] - ls;
        o1.x = ev[4] - ls; o1.y = ev[5] - ls; o1.z = ev[6] - ls; o1.w = ev[7] - ls;
        *(float4*)(out + (size_t)d * 32 + 8 * jc) = o0;
        *(float4*)(out + (size_t)d * 32 + 8 * jc + 4) = o1;
    }
}

// ---------------- launch ----------------

extern "C" void kernel_launch(void* const* d_in, const int* in_sizes, int n_in,
                              void* d_out, int out_size, void* d_ws, size_t ws_size,
                              hipStream_t stream) {
    const float* x   = (const float*)d_in[0];
    const int*   ei  = (const int*)d_in[1];
    const float* W1  = (const float*)d_in[2];
    const float* as1 = (const float*)d_in[3];
    const float* ad1 = (const float*)d_in[4];
    const float* b1  = (const float*)d_in[5];
    const float* W2  = (const float*)d_in[6];
    const float* as2 = (const float*)d_in[7];
    const float* ad2 = (const float*)d_in[8];
    const float* b2  = (const float*)d_in[9];
    float* out = (float*)d_out;
    int N = in_sizes[0] / 128;
    int E = in_sizes[1] / 2;

    char* base = (char*)d_ws;
    size_t off = 0;
    auto alloc = [&](size_t bytes) -> char* {
        char* p = base + off;
        off = (off + bytes + 255) & ~(size_t)255;
        return p;
    };
    __half* h1h   = (__half*)alloc((size_t)N * 64 * 2);
    __half* h1o   = (__half*)alloc((size_t)N * 64 * 2);
    __half* h2h   = (__half*)alloc((size_t)N * 128 * 2);
    float* alsrc1 = (float*)alloc((size_t)N * 4 * 4);
    float* aldst1 = (float*)alloc((size_t)N * 4 * 4);
    float* alsrc2 = (float*)alloc((size_t)N * 4 * 4);
    float* aldst2 = (float*)alloc((size_t)N * 4 * 4);
    int* cnt  = (int*)alloc((size_t)N * 4);
    int* rp   = (int*)alloc((size_t)N * 4);
    int* perm = (int*)alloc((size_t)N * 4);
    int* curA = (int*)alloc(256 * 4);
    int* dbins = (int*)alloc(256 * 4);
    int* dcur  = (int*)alloc(256 * 4);
    int* bs   = (int*)alloc(1024 * 4);
    int* srccol = (int*)alloc((size_t)E * 4);
    uint2* pairs = (uint2*)alloc((size_t)E * 8);

    int nbk = (N + 511) >> 9;       // 512-node buckets
    int ntilesA = (E + TILE - 1) / TILE;
    int nb = (N + 255) / 256;

    hipMemsetAsync(cnt, 0, (size_t)N * 4, stream);
    hipMemsetAsync(dbins, 0, 256 * 4, stream);
    hist_k<<<(E + 255) / 256, 256, 0, stream>>>(ei, cnt, E);
    scan1_k<<<nb, 256, 0, stream>>>(cnt, rp, bs, N);
    scan2_k<<<1, 1024, 0, stream>>>(bs, nb);
    scan3_k<<<nb, 256, 0, stream>>>(rp, bs, N);
    initA_k<<<1, 256, 0, stream>>>(rp, curA, nbk);
    dhist_k<<<nb, 256, 0, stream>>>(cnt, dbins, N);
    dscan_k<<<1, 256, 0, stream>>>(dbins, dcur);
    dperm_k<<<nb, 256, 0, stream>>>(cnt, dcur, perm, N);
    partA_k<<<ntilesA, 256, 0, stream>>>(ei, curA, pairs, E, nbk);
    partB_pairs_k<<<nbk, 256, 0, stream>>>(pairs, rp, srccol, E, N);

    gemm1_k<<<768, 256, 0, stream>>>(x, W1, as1, ad1, h1h, alsrc1, aldst1, N);
    node1_k<<<(N + 15) / 16, 256, 0, stream>>>(h1h, srccol, perm, alsrc1, aldst1, rp, cnt, b1, h1o, N);
    gemm2_k<<<768, 256, 0, stream>>>(h1o, W2, as2, ad2, h2h, alsrc2, aldst2, N);
    node2_k<<<(N + 15) / 16, 256, 0, stream>>>(h2h, srccol, perm, alsrc2, aldst2, rp, cnt, b2, out, N);
}

// Round 10
// 547.069 us; speedup vs baseline: 1.6944x; 1.6944x over previous
//
#include <hip/hip_runtime.h>
#include <hip/hip_fp16.h>
#include <cstdint>
#include <cstddef>

#define NEG 0.2f
#define TILE 4096   // edges per partition tile

// ---------------- CSR build: hist + scan ----------------

__global__ __launch_bounds__(256) void hist_k(const int* __restrict__ ei, int* __restrict__ cnt, int E) {
    int i = blockIdx.x * 256 + threadIdx.x;
    if (i < E) atomicAdd(&cnt[__builtin_nontemporal_load(ei + E + i)], 1);
}

__global__ __launch_bounds__(256) void scan1_k(const int* __restrict__ cnt, int* __restrict__ rp,
                                               int* __restrict__ bs, int N) {
    __shared__ int sm[256];
    int t = threadIdx.x, i = blockIdx.x * 256 + t;
    int v = (i < N) ? cnt[i] : 0;
    sm[t] = v; __syncthreads();
    for (int off = 1; off < 256; off <<= 1) {
        int u = (t >= off) ? sm[t - off] : 0;
        __syncthreads();
        sm[t] += u;
        __syncthreads();
    }
    if (i < N) rp[i] = sm[t] - v;          // exclusive within block
    if (t == 255) bs[blockIdx.x] = sm[255];
}

__global__ __launch_bounds__(1024) void scan2_k(int* __restrict__ bs, int nb) {
    __shared__ int sm[1024];
    int t = threadIdx.x;
    int v = (t < nb) ? bs[t] : 0;
    sm[t] = v; __syncthreads();
    for (int off = 1; off < 1024; off <<= 1) {
        int u = (t >= off) ? sm[t - off] : 0;
        __syncthreads();
        sm[t] += u;
        __syncthreads();
    }
    if (t < nb) bs[t] = sm[t] - v;         // exclusive block offsets
}

__global__ __launch_bounds__(256) void scan3_k(int* __restrict__ rp, const int* __restrict__ bs, int N) {
    int i = blockIdx.x * 256 + threadIdx.x;
    if (i < N) rp[i] += bs[blockIdx.x];
}

__global__ __launch_bounds__(256) void initA_k(const int* __restrict__ rp, int* __restrict__ curA, int nbk) {
    int b = threadIdx.x;
    if (b < nbk) curA[b] = rp[b << 9];
}

// ---------------- Degree-sorted node permutation (contention-free counting sort) ----------------
// dhist2: per-block LDS histogram -> blockhist[block][bin]  (no global atomics)

__global__ __launch_bounds__(256) void dhist2_k(const int* __restrict__ cnt, int* __restrict__ blockhist, int N) {
    __shared__ int sh[256];
    int t = threadIdx.x;
    sh[t] = 0;
    __syncthreads();
    int i = blockIdx.x * 256 + t;
    if (i < N) atomicAdd(&sh[min(cnt[i], 255)], 1);
    __syncthreads();
    blockhist[blockIdx.x * 256 + t] = sh[t];
}

// dscan2: thread t = bin t. Sequential scan over blocks (coalesced), then cross-bin
// exclusive scan, then add bin base into every blockoff entry.
__global__ __launch_bounds__(256) void dscan2_k(const int* __restrict__ blockhist, int* __restrict__ blockoff,
                                                int nb) {
    __shared__ int sm[256];
    int t = threadIdx.x;
    int running = 0;
    for (int b = 0; b < nb; b++) {
        int v = blockhist[b * 256 + t];
        blockoff[b * 256 + t] = running;
        running += v;
    }
    sm[t] = running;
    __syncthreads();
    for (int off = 1; off < 256; off <<= 1) {
        int u = (t >= off) ? sm[t - off] : 0;
        __syncthreads();
        sm[t] += u;
        __syncthreads();
    }
    int base = sm[t] - running;   // exclusive across bins
    for (int b = 0; b < nb; b++) blockoff[b * 256 + t] += base;
}

// dperm2: LDS cursors seeded from blockoff; placement with LDS atomics only.
__global__ __launch_bounds__(256) void dperm2_k(const int* __restrict__ cnt, const int* __restrict__ blockoff,
                                                int* __restrict__ perm, int N) {
    __shared__ int cur[256];
    int t = threadIdx.x;
    cur[t] = blockoff[blockIdx.x * 256 + t];
    __syncthreads();
    int i = blockIdx.x * 256 + t;
    if (i < N) {
        int b = min(cnt[i], 255);
        int pos = atomicAdd(&cur[b], 1);
        perm[pos] = i;
    }
}

// ---------------- Phase A: LDS-staged partition of edges into 512-node buckets ----------------

__global__ __launch_bounds__(256) void partA_k(const int* __restrict__ ei, int* __restrict__ curA,
                                               uint2* __restrict__ pairs, int E, int nbk) {
    __shared__ int scnt[256];
    __shared__ int sc[256];
    __shared__ int sbase[256];
    __shared__ int gbase[256];
    __shared__ int cur2[256];
    __shared__ int ssrc[TILE];
    __shared__ int sdst[TILE];
    int t = threadIdx.x;
    int ntiles = (E + TILE - 1) / TILE;
    for (int tile = blockIdx.x; tile < ntiles; tile += gridDim.x) {
        int base = tile * TILE;
        int cntE = min(TILE, E - base);
        scnt[t] = 0;
        __syncthreads();
        int mys[16], myd[16];
        #pragma unroll
        for (int j = 0; j < 16; j++) {
            int i = base + t + 256 * j;
            int s = 0, d = -1;
            if (i < E) {
                s = __builtin_nontemporal_load(ei + i);
                d = __builtin_nontemporal_load(ei + E + i);
            }
            mys[j] = s; myd[j] = d;
            if (d >= 0) atomicAdd(&scnt[d >> 9], 1);
        }
        __syncthreads();
        sc[t] = scnt[t];
        __syncthreads();
        for (int off = 1; off < 256; off <<= 1) {
            int u = (t >= off) ? sc[t - off] : 0;
            __syncthreads();
            sc[t] += u;
            __syncthreads();
        }
        int myb = sc[t] - scnt[t];
        sbase[t] = myb;
        cur2[t] = myb;
        if (t < nbk && scnt[t] > 0) gbase[t] = atomicAdd(&curA[t], scnt[t]);
        __syncthreads();
        #pragma unroll
        for (int j = 0; j < 16; j++) {
            int d = myd[j];
            if (d >= 0) {
                int b = d >> 9;
                int pos = atomicAdd(&cur2[b], 1);
                ssrc[pos] = mys[j];
                sdst[pos] = d;
            }
        }
        __syncthreads();
        for (int i = t; i < cntE; i += 256) {
            int d = sdst[i];
            int b = d >> 9;
            int addr = gbase[b] + (i - sbase[b]);
            pairs[addr] = make_uint2((unsigned)ssrc[i], (unsigned)d);
        }
        __syncthreads();
    }
}

// ---------------- Phase B: per-bucket scatter to per-node CSR positions ----------------

__global__ __launch_bounds__(256) void partB_pairs_k(const uint2* __restrict__ pin, const int* __restrict__ rp,
                                                     int* __restrict__ srcout, int E, int N) {
    __shared__ int cur[512];
    int b = blockIdx.x;
    int t = threadIdx.x;
    int d0 = b << 9;
    cur[t] = 0; cur[t + 256] = 0;
    __syncthreads();
    int hi = d0 + 512;
    int ebase = rp[d0];
    int eend = (hi >= N) ? E : rp[hi];
    for (int j = ebase + t; j < eend; j += 256) {
        uint2 p = pin[j];
        int d = (int)p.y;
        int pos = rp[d] + atomicAdd(&cur[d - d0], 1);
        srcout[pos] = (int)p.x;
    }
}

// ---------------- Layer 1 GEMM: h1 = x @ W1 (fp16 out), register-tiled ----------------

__global__ __launch_bounds__(256) void gemm1_k(const float* __restrict__ x, const float* __restrict__ W,
                                               const float* __restrict__ a_src, const float* __restrict__ a_dst,
                                               __half* __restrict__ h, float* __restrict__ alsrc,
                                               float* __restrict__ aldst, int N) {
    __shared__ float Bs[128 * 64];
    __shared__ float xs[64][68];
    int t = threadIdx.x;
    for (int i = t; i < 128 * 64 / 4; i += 256)
        ((float4*)Bs)[i] = ((const float4*)W)[i];
    int ct = t & 15, rt = t >> 4;
    int head = ct >> 2, cq = ct & 3;
    float asv[4], adv[4];
    #pragma unroll
    for (int j = 0; j < 4; j++) {
        asv[j] = a_src[head * 16 + 4 * cq + j];
        adv[j] = a_dst[head * 16 + 4 * cq + j];
    }
    int ntiles = (N + 63) >> 6;
    for (int tile = blockIdx.x; tile < ntiles; tile += gridDim.x) {
        int r0 = tile << 6;
        float acc[4][4];
        #pragma unroll
        for (int i = 0; i < 4; i++)
            #pragma unroll
            for (int j = 0; j < 4; j++) acc[i][j] = 0.f;
        for (int kc = 0; kc < 128; kc += 64) {
            __syncthreads();
            int srow = t >> 4, sf4 = t & 15;
            #pragma unroll
            for (int p = 0; p < 4; p++) {
                int r = r0 + srow + 16 * p;
                float4 v = make_float4(0.f, 0.f, 0.f, 0.f);
                if (r < N) v = *(const float4*)(x + (size_t)r * 128 + kc + 4 * sf4);
                *(float4*)&xs[srow + 16 * p][4 * sf4] = v;
            }
            __syncthreads();
            #pragma unroll 4
            for (int k = 0; k < 64; k++) {
                float4 bv = *(float4*)&Bs[(kc + k) * 64 + 4 * ct];
                #pragma unroll
                for (int i = 0; i < 4; i++) {
                    float xv = xs[4 * rt + i][k];
                    acc[i][0] = fmaf(xv, bv.x, acc[i][0]);
                    acc[i][1] = fmaf(xv, bv.y, acc[i][1]);
                    acc[i][2] = fmaf(xv, bv.z, acc[i][2]);
                    acc[i][3] = fmaf(xv, bv.w, acc[i][3]);
                }
            }
        }
        #pragma unroll
        for (int i = 0; i < 4; i++) {
            int r = r0 + 4 * rt + i;
            float ps = 0.f, pd = 0.f;
            #pragma unroll
            for (int j = 0; j < 4; j++) {
                ps = fmaf(acc[i][j], asv[j], ps);
                pd = fmaf(acc[i][j], adv[j], pd);
            }
            ps += __shfl_xor(ps, 1); ps += __shfl_xor(ps, 2);
            pd += __shfl_xor(pd, 1); pd += __shfl_xor(pd, 2);
            if (r < N) {
                __half2 h0 = __floats2half2_rn(acc[i][0], acc[i][1]);
                __half2 h1 = __floats2half2_rn(acc[i][2], acc[i][3]);
                *(__half2*)(h + (size_t)r * 64 + 4 * ct) = h0;
                *(__half2*)(h + (size_t)r * 64 + 4 * ct + 2) = h1;
                if (cq == 0) { alsrc[r * 4 + head] = ps; aldst[r * 4 + head] = pd; }
            }
        }
    }
}

// ---------------- Layer 1 node aggregation: quarter-wave per node, degree-sorted ----------------

__global__ __launch_bounds__(256) void node1_k(const __half* __restrict__ h, const int* __restrict__ srccol,
                                               const int* __restrict__ perm,
                                               const float* __restrict__ alsrc, const float* __restrict__ aldst,
                                               const int* __restrict__ rp, const int* __restrict__ cnt,
                                               const float* __restrict__ bias, __half* __restrict__ out, int N) {
    int t = threadIdx.x;
    int idx = (blockIdx.x * 256 + t) >> 4;
    if (idx >= N) return;
    int d = perm[idx];
    int c = t & 15;
    int hc = c >> 2;
    const __half2* hb = (const __half2*)h;
    unsigned co = 2u * c;
    float ad = aldst[d * 4 + hc];
    float e = alsrc[d * 4 + hc] + ad;
    float w = __expf(e > 0.f ? e : NEG * e);
    float den = w;
    __half2 wp = __float2half2_rn(w);
    uint2 u = *(const uint2*)(hb + ((unsigned)d << 5) + co);
    __half2 acc0 = __hmul2(wp, *(__half2*)&u.x);
    __half2 acc1 = __hmul2(wp, *(__half2*)&u.y);
    int start = rp[d], deg = cnt[d];
    int i = 0;
    for (; i + 1 < deg; i += 2) {
        int s0 = srccol[start + i];
        int s1 = srccol[start + i + 1];
        uint2 u0 = *(const uint2*)(hb + ((unsigned)s0 << 5) + co);
        uint2 u1 = *(const uint2*)(hb + ((unsigned)s1 << 5) + co);
        float e0 = alsrc[s0 * 4 + hc] + ad;
        float e1 = alsrc[s1 * 4 + hc] + ad;
        float w0 = __expf(e0 > 0.f ? e0 : NEG * e0);
        float w1 = __expf(e1 > 0.f ? e1 : NEG * e1);
        den += w0 + w1;
        __half2 wp0 = __float2half2_rn(w0), wp1 = __float2half2_rn(w1);
        acc0 = __hfma2(wp0, *(__half2*)&u0.x, acc0);
        acc1 = __hfma2(wp0, *(__half2*)&u0.y, acc1);
        acc0 = __hfma2(wp1, *(__half2*)&u1.x, acc0);
        acc1 = __hfma2(wp1, *(__half2*)&u1.y, acc1);
    }
    if (i < deg) {
        int s = srccol[start + i];
        uint2 us = *(const uint2*)(hb + ((unsigned)s << 5) + co);
        float es = alsrc[s * 4 + hc] + ad;
        float ws = __expf(es > 0.f ? es : NEG * es);
        den += ws;
        __half2 wps = __float2half2_rn(ws);
        acc0 = __hfma2(wps, *(__half2*)&us.x, acc0);
        acc1 = __hfma2(wps, *(__half2*)&us.y, acc1);
    }
    float inv = 1.f / den;
    float2 f0 = __half22float2(acc0), f1 = __half22float2(acc1);
    float4 b = *(const float4*)(bias + 4 * c);
    __half2 o0 = __floats2half2_rn(f0.x * inv + b.x, f0.y * inv + b.y);
    __half2 o1 = __floats2half2_rn(f1.x * inv + b.z, f1.y * inv + b.w);
    uint2 o; o.x = *(unsigned*)&o0; o.y = *(unsigned*)&o1;
    *(uint2*)(out + (size_t)d * 64 + 4 * c) = o;
}

// ---------------- Layer 2 GEMM: h2 = h1o(fp16) @ W2 (fp16 out), register-tiled ----------------

__global__ __launch_bounds__(256) void gemm2_k(const __half* __restrict__ xh, const float* __restrict__ W,
                                               const float* __restrict__ a_src, const float* __restrict__ a_dst,
                                               __half* __restrict__ h, float* __restrict__ alsrc,
                                               float* __restrict__ aldst, int N) {
    __shared__ float Bs[64 * 128];
    __shared__ float xs[64][68];
    int t = threadIdx.x;
    for (int i = t; i < 64 * 128 / 4; i += 256)
        ((float4*)Bs)[i] = ((const float4*)W)[i];
    int ct = t & 15, rt = t >> 4;
    int hA = ct >> 3, cq = ct & 7;
    float asA[4], adA[4], asB[4], adB[4];
    #pragma unroll
    for (int j = 0; j < 4; j++) {
        asA[j] = a_src[hA * 32 + 4 * cq + j];
        adA[j] = a_dst[hA * 32 + 4 * cq + j];
        asB[j] = a_src[(2 + hA) * 32 + 4 * cq + j];
        adB[j] = a_dst[(2 + hA) * 32 + 4 * cq + j];
    }
    int ntiles = (N + 63) >> 6;
    for (int tile = blockIdx.x; tile < ntiles; tile += gridDim.x) {
        int r0 = tile << 6;
        float accA[4][4], accB[4][4];
        #pragma unroll
        for (int i = 0; i < 4; i++)
            #pragma unroll
            for (int j = 0; j < 4; j++) { accA[i][j] = 0.f; accB[i][j] = 0.f; }
        __syncthreads();
        int srow = t >> 3, su = t & 7;
        #pragma unroll
        for (int p = 0; p < 2; p++) {
            int r = r0 + srow + 32 * p;
            float2 g0 = make_float2(0.f, 0.f), g1 = g0, g2 = g0, g3 = g0;
            if (r < N) {
                uint4 u = *(const uint4*)(xh + (size_t)r * 64 + 8 * su);
                const __half2* hp = (const __half2*)&u;
                g0 = __half22float2(hp[0]); g1 = __half22float2(hp[1]);
                g2 = __half22float2(hp[2]); g3 = __half22float2(hp[3]);
            }
            *(float4*)&xs[srow + 32 * p][8 * su] = make_float4(g0.x, g0.y, g1.x, g1.y);
            *(float4*)&xs[srow + 32 * p][8 * su + 4] = make_float4(g2.x, g2.y, g3.x, g3.y);
        }
        __syncthreads();
        #pragma unroll 4
        for (int k = 0; k < 64; k++) {
            float4 bA = *(float4*)&Bs[k * 128 + 4 * ct];
            float4 bB = *(float4*)&Bs[k * 128 + 64 + 4 * ct];
            #pragma unroll
            for (int i = 0; i < 4; i++) {
                float xv = xs[4 * rt + i][k];
                accA[i][0] = fmaf(xv, bA.x, accA[i][0]);
                accA[i][1] = fmaf(xv, bA.y, accA[i][1]);
                accA[i][2] = fmaf(xv, bA.z, accA[i][2]);
                accA[i][3] = fmaf(xv, bA.w, accA[i][3]);
                accB[i][0] = fmaf(xv, bB.x, accB[i][0]);
                accB[i][1] = fmaf(xv, bB.y, accB[i][1]);
                accB[i][2] = fmaf(xv, bB.z, accB[i][2]);
                accB[i][3] = fmaf(xv, bB.w, accB[i][3]);
            }
        }
        #pragma unroll
        for (int i = 0; i < 4; i++) {
            int r = r0 + 4 * rt + i;
            float psA = 0.f, pdA = 0.f, psB = 0.f, pdB = 0.f;
            #pragma unroll
            for (int j = 0; j < 4; j++) {
                psA = fmaf(accA[i][j], asA[j], psA);
                pdA = fmaf(accA[i][j], adA[j], pdA);
                psB = fmaf(accB[i][j], asB[j], psB);
                pdB = fmaf(accB[i][j], adB[j], pdB);
            }
            #pragma unroll
            for (int off = 1; off <= 4; off <<= 1) {
                psA += __shfl_xor(psA, off); pdA += __shfl_xor(pdA, off);
                psB += __shfl_xor(psB, off); pdB += __shfl_xor(pdB, off);
            }
            if (r < N) {
                __half2 hA0 = __floats2half2_rn(accA[i][0], accA[i][1]);
                __half2 hA1 = __floats2half2_rn(accA[i][2], accA[i][3]);
                __half2 hB0 = __floats2half2_rn(accB[i][0], accB[i][1]);
                __half2 hB1 = __floats2half2_rn(accB[i][2], accB[i][3]);
                *(__half2*)(h + (size_t)r * 128 + 4 * ct) = hA0;
                *(__half2*)(h + (size_t)r * 128 + 4 * ct + 2) = hA1;
                *(__half2*)(h + (size_t)r * 128 + 64 + 4 * ct) = hB0;
                *(__half2*)(h + (size_t)r * 128 + 64 + 4 * ct + 2) = hB1;
                if (cq == 0) {
                    alsrc[r * 4 + hA] = psA;     alsrc[r * 4 + 2 + hA] = psB;
                    aldst[r * 4 + hA] = pdA;     aldst[r * 4 + 2 + hA] = pdB;
                }
            }
        }
    }
}

// ---------------- Layer 2 node aggregation: quarter-wave per node, degree-sorted + epilogue ----------------

__global__ __launch_bounds__(256) void node2_k(const __half* __restrict__ h, const int* __restrict__ srccol,
                                               const int* __restrict__ perm,
                                               const float* __restrict__ alsrc, const float* __restrict__ aldst,
                                               const int* __restrict__ rp, const int* __restrict__ cnt,
                                               const float* __restrict__ bias, float* __restrict__ out, int N) {
    int t = threadIdx.x;
    int idx = (blockIdx.x * 256 + t) >> 4;
    if (idx >= N) return;
    int d = perm[idx];
    int c = t & 15;
    int hc = c >> 2, jc = c & 3;
    const __half2* hb = (const __half2*)h;
    unsigned co = 4u * c;
    float ad = aldst[d * 4 + hc];
    float e = alsrc[d * 4 + hc] + ad;
    float w = __expf(e > 0.f ? e : NEG * e);
    float den = w;
    __half2 wp = __float2half2_rn(w);
    uint4 u = *(const uint4*)(hb + ((unsigned)d << 6) + co);
    const __half2* hp = (const __half2*)&u;
    __half2 acc[4];
    #pragma unroll
    for (int j = 0; j < 4; j++) acc[j] = __hmul2(wp, hp[j]);
    int start = rp[d], deg = cnt[d];
    int i = 0;
    for (; i + 1 < deg; i += 2) {
        int s0 = srccol[start + i];
        int s1 = srccol[start + i + 1];
        uint4 u0 = *(const uint4*)(hb + ((unsigned)s0 << 6) + co);
        uint4 u1 = *(const uint4*)(hb + ((unsigned)s1 << 6) + co);
        float e0 = alsrc[s0 * 4 + hc] + ad;
        float e1 = alsrc[s1 * 4 + hc] + ad;
        float w0 = __expf(e0 > 0.f ? e0 : NEG * e0);
        float w1 = __expf(e1 > 0.f ? e1 : NEG * e1);
        den += w0 + w1;
        __half2 wp0 = __float2half2_rn(w0), wp1 = __float2half2_rn(w1);
        const __half2* hp0 = (const __half2*)&u0;
        const __half2* hp1 = (const __half2*)&u1;
        #pragma unroll
        for (int j = 0; j < 4; j++) acc[j] = __hfma2(wp0, hp0[j], acc[j]);
        #pragma unroll
        for (int j = 0; j < 4; j++) acc[j] = __hfma2(wp1, hp1[j], acc[j]);
    }
    if (i < deg) {
        int s = srccol[start + i];
        uint4 us = *(const uint4*)(hb + ((unsigned)s << 6) + co);
        float es = alsrc[s * 4 + hc] + ad;
        float ws = __expf(es > 0.f ? es : NEG * es);
        den += ws;
        __half2 wps = __float2half2_rn(ws);
        const __half2* hps = (const __half2*)&us;
        #pragma unroll
        for (int j = 0; j < 4; j++) acc[j] = __hfma2(wps, hps[j], acc[j]);
    }
    float inv = 1.f / den;
    float v[8];
    #pragma unroll
    for (int j = 0; j < 4; j++) {
        float2 f = __half22float2(acc[j]);
        v[2 * j] = f.x * inv; v[2 * j + 1] = f.y * inv;
    }
    // head-mean: sum across lanes with same jc (lane bits 4 and 8)
    #pragma unroll
    for (int off = 4; off <= 8; off <<= 1) {
        #pragma unroll
        for (int j = 0; j < 8; j++) v[j] += __shfl_xor(v[j], off);
    }
    float ev[8];
    #pragma unroll
    for (int j = 0; j < 8; j++) {
        float val = 0.25f * v[j] + bias[8 * jc + j];
        ev[j] = val > 0.f ? val : __expf(val) - 1.f;
    }
    float mx = ev[0];
    #pragma unroll
    for (int j = 1; j < 8; j++) mx = fmaxf(mx, ev[j]);
    #pragma unroll
    for (int off = 1; off <= 2; off <<= 1) mx = fmaxf(mx, __shfl_xor(mx, off));
    float sum = 0.f;
    #pragma unroll
    for (int j = 0; j < 8; j++) sum += __expf(ev[j] - mx);
    #pragma unroll
    for (int off = 1; off <= 2; off <<= 1) sum += __shfl_xor(sum, off);
    float ls = mx + __logf(sum);
    if (c < 4) {
        float4 o0, o1;
        o0.x = ev[0] - ls; o0.y = ev[1] - ls; o0.z = ev[2] - ls; o0.w = ev[3] - ls;
        o1.x = ev[4] - ls; o1.y = ev[5] - ls; o1.z = ev[6] - ls; o1.w = ev[7] - ls;
        *(float4*)(out + (size_t)d * 32 + 8 * jc) = o0;
        *(float4*)(out + (size_t)d * 32 + 8 * jc + 4) = o1;
    }
}

// ---------------- launch ----------------

extern "C" void kernel_launch(void* const* d_in, const int* in_sizes, int n_in,
                              void* d_out, int out_size, void* d_ws, size_t ws_size,
                              hipStream_t stream) {
    const float* x   = (const float*)d_in[0];
    const int*   ei  = (const int*)d_in[1];
    const float* W1  = (const float*)d_in[2];
    const float* as1 = (const float*)d_in[3];
    const float* ad1 = (const float*)d_in[4];
    const float* b1  = (const float*)d_in[5];
    const float* W2  = (const float*)d_in[6];
    const float* as2 = (const float*)d_in[7];
    const float* ad2 = (const float*)d_in[8];
    const float* b2  = (const float*)d_in[9];
    float* out = (float*)d_out;
    int N = in_sizes[0] / 128;
    int E = in_sizes[1] / 2;

    char* base = (char*)d_ws;
    size_t off = 0;
    auto alloc = [&](size_t bytes) -> char* {
        char* p = base + off;
        off = (off + bytes + 255) & ~(size_t)255;
        return p;
    };
    __half* h1h   = (__half*)alloc((size_t)N * 64 * 2);
    __half* h1o   = (__half*)alloc((size_t)N * 64 * 2);
    __half* h2h   = (__half*)alloc((size_t)N * 128 * 2);
    float* alsrc1 = (float*)alloc((size_t)N * 4 * 4);
    float* aldst1 = (float*)alloc((size_t)N * 4 * 4);
    float* alsrc2 = (float*)alloc((size_t)N * 4 * 4);
    float* aldst2 = (float*)alloc((size_t)N * 4 * 4);
    int* cnt  = (int*)alloc((size_t)N * 4);
    int* rp   = (int*)alloc((size_t)N * 4);
    int* perm = (int*)alloc((size_t)N * 4);
    int* curA = (int*)alloc(256 * 4);
    int* bs   = (int*)alloc(1024 * 4);
    int* srccol = (int*)alloc((size_t)E * 4);
    uint2* pairs = (uint2*)alloc((size_t)E * 8);

    int nb = (N + 255) / 256;
    int* blockhist = (int*)alloc((size_t)nb * 256 * 4);
    int* blockoff  = (int*)alloc((size_t)nb * 256 * 4);

    int nbk = (N + 511) >> 9;       // 512-node buckets
    int ntilesA = (E + TILE - 1) / TILE;

    hipMemsetAsync(cnt, 0, (size_t)N * 4, stream);
    hist_k<<<(E + 255) / 256, 256, 0, stream>>>(ei, cnt, E);
    scan1_k<<<nb, 256, 0, stream>>>(cnt, rp, bs, N);
    scan2_k<<<1, 1024, 0, stream>>>(bs, nb);
    scan3_k<<<nb, 256, 0, stream>>>(rp, bs, N);
    initA_k<<<1, 256, 0, stream>>>(rp, curA, nbk);
    dhist2_k<<<nb, 256, 0, stream>>>(cnt, blockhist, N);
    dscan2_k<<<1, 256, 0, stream>>>(blockhist, blockoff, nb);
    dperm2_k<<<nb, 256, 0, stream>>>(cnt, blockoff, perm, N);
    partA_k<<<ntilesA, 256, 0, stream>>>(ei, curA, pairs, E, nbk);
    partB_pairs_k<<<nbk, 256, 0, stream>>>(pairs, rp, srccol, E, N);

    gemm1_k<<<768, 256, 0, stream>>>(x, W1, as1, ad1, h1h, alsrc1, aldst1, N);
    node1_k<<<(N + 15) / 16, 256, 0, stream>>>(h1h, srccol, perm, alsrc1, aldst1, rp, cnt, b1, h1o, N);
    gemm2_k<<<768, 256, 0, stream>>>(h1o, W2, as2, ad2, h2h, alsrc2, aldst2, N);
    node2_k<<<(N + 15) / 16, 256, 0, stream>>>(h2h, srccol, perm, alsrc2, aldst2, rp, cnt, b2, out, N);
}

// Round 11
// 381.853 us; speedup vs baseline: 2.4275x; 1.4327x over previous
//
#include <hip/hip_runtime.h>
#include <hip/hip_fp16.h>
#include <cstdint>
#include <cstddef>

#define NEG 0.2f
#define TILE 4096   // edges per partition tile

// ---------------- CSR build: hist + scan ----------------

__global__ __launch_bounds__(256) void hist_k(const int* __restrict__ ei, int* __restrict__ cnt, int E) {
    int i = blockIdx.x * 256 + threadIdx.x;
    if (i < E) atomicAdd(&cnt[__builtin_nontemporal_load(ei + E + i)], 1);
}

__global__ __launch_bounds__(256) void scan1_k(const int* __restrict__ cnt, int* __restrict__ rp,
                                               int* __restrict__ bs, int N) {
    __shared__ int sm[256];
    int t = threadIdx.x, i = blockIdx.x * 256 + t;
    int v = (i < N) ? cnt[i] : 0;
    sm[t] = v; __syncthreads();
    for (int off = 1; off < 256; off <<= 1) {
        int u = (t >= off) ? sm[t - off] : 0;
        __syncthreads();
        sm[t] += u;
        __syncthreads();
    }
    if (i < N) rp[i] = sm[t] - v;          // exclusive within block
    if (t == 255) bs[blockIdx.x] = sm[255];
}

__global__ __launch_bounds__(1024) void scan2_k(int* __restrict__ bs, int nb) {
    __shared__ int sm[1024];
    int t = threadIdx.x;
    int v = (t < nb) ? bs[t] : 0;
    sm[t] = v; __syncthreads();
    for (int off = 1; off < 1024; off <<= 1) {
        int u = (t >= off) ? sm[t - off] : 0;
        __syncthreads();
        sm[t] += u;
        __syncthreads();
    }
    if (t < nb) bs[t] = sm[t] - v;         // exclusive block offsets
}

__global__ __launch_bounds__(256) void scan3_k(int* __restrict__ rp, const int* __restrict__ bs, int N) {
    int i = blockIdx.x * 256 + threadIdx.x;
    if (i < N) rp[i] += bs[blockIdx.x];
}

__global__ __launch_bounds__(256) void initA_k(const int* __restrict__ rp, int* __restrict__ curA, int nbk) {
    int b = threadIdx.x;
    if (b < nbk) curA[b] = rp[b << 9];
}

// ---------------- Phase A: LDS-staged partition of edges into 512-node buckets ----------------

__global__ __launch_bounds__(256) void partA_k(const int* __restrict__ ei, int* __restrict__ curA,
                                               uint2* __restrict__ pairs, int E, int nbk) {
    __shared__ int scnt[256];
    __shared__ int sc[256];
    __shared__ int sbase[256];
    __shared__ int gbase[256];
    __shared__ int cur2[256];
    __shared__ int ssrc[TILE];
    __shared__ int sdst[TILE];
    int t = threadIdx.x;
    int ntiles = (E + TILE - 1) / TILE;
    for (int tile = blockIdx.x; tile < ntiles; tile += gridDim.x) {
        int base = tile * TILE;
        int cntE = min(TILE, E - base);
        scnt[t] = 0;
        __syncthreads();
        int mys[16], myd[16];
        #pragma unroll
        for (int j = 0; j < 16; j++) {
            int i = base + t + 256 * j;
            int s = 0, d = -1;
            if (i < E) {
                s = __builtin_nontemporal_load(ei + i);
                d = __builtin_nontemporal_load(ei + E + i);
            }
            mys[j] = s; myd[j] = d;
            if (d >= 0) atomicAdd(&scnt[d >> 9], 1);
        }
        __syncthreads();
        sc[t] = scnt[t];
        __syncthreads();
        for (int off = 1; off < 256; off <<= 1) {
            int u = (t >= off) ? sc[t - off] : 0;
            __syncthreads();
            sc[t] += u;
            __syncthreads();
        }
        int myb = sc[t] - scnt[t];
        sbase[t] = myb;
        cur2[t] = myb;
        if (t < nbk && scnt[t] > 0) gbase[t] = atomicAdd(&curA[t], scnt[t]);
        __syncthreads();
        #pragma unroll
        for (int j = 0; j < 16; j++) {
            int d = myd[j];
            if (d >= 0) {
                int b = d >> 9;
                int pos = atomicAdd(&cur2[b], 1);
                ssrc[pos] = mys[j];
                sdst[pos] = d;
            }
        }
        __syncthreads();
        for (int i = t; i < cntE; i += 256) {
            int d = sdst[i];
            int b = d >> 9;
            int addr = gbase[b] + (i - sbase[b]);
            pairs[addr] = make_uint2((unsigned)ssrc[i], (unsigned)d);
        }
        __syncthreads();
    }
}

// ---------------- Phase B: per-bucket scatter to per-node CSR positions ----------------

__global__ __launch_bounds__(256) void partB_pairs_k(const uint2* __restrict__ pin, const int* __restrict__ rp,
                                                     int* __restrict__ srcout, int E, int N) {
    __shared__ int cur[512];
    int b = blockIdx.x;
    int t = threadIdx.x;
    int d0 = b << 9;
    cur[t] = 0; cur[t + 256] = 0;
    __syncthreads();
    int hi = d0 + 512;
    int ebase = rp[d0];
    int eend = (hi >= N) ? E : rp[hi];
    for (int j = ebase + t; j < eend; j += 256) {
        uint2 p = pin[j];
        int d = (int)p.y;
        int pos = rp[d] + atomicAdd(&cur[d - d0], 1);
        srcout[pos] = (int)p.x;
    }
}

// ---------------- Layer 1 GEMM: h1 = x @ W1 (fp16 out), register-tiled ----------------

__global__ __launch_bounds__(256) void gemm1_k(const float* __restrict__ x, const float* __restrict__ W,
                                               const float* __restrict__ a_src, const float* __restrict__ a_dst,
                                               __half* __restrict__ h, float* __restrict__ alsrc,
                                               float* __restrict__ aldst, int N) {
    __shared__ float Bs[128 * 64];
    __shared__ float xs[64][68];
    int t = threadIdx.x;
    for (int i = t; i < 128 * 64 / 4; i += 256)
        ((float4*)Bs)[i] = ((const float4*)W)[i];
    int ct = t & 15, rt = t >> 4;
    int head = ct >> 2, cq = ct & 3;
    float asv[4], adv[4];
    #pragma unroll
    for (int j = 0; j < 4; j++) {
        asv[j] = a_src[head * 16 + 4 * cq + j];
        adv[j] = a_dst[head * 16 + 4 * cq + j];
    }
    int ntiles = (N + 63) >> 6;
    for (int tile = blockIdx.x; tile < ntiles; tile += gridDim.x) {
        int r0 = tile << 6;
        float acc[4][4];
        #pragma unroll
        for (int i = 0; i < 4; i++)
            #pragma unroll
            for (int j = 0; j < 4; j++) acc[i][j] = 0.f;
        for (int kc = 0; kc < 128; kc += 64) {
            __syncthreads();
            int srow = t >> 4, sf4 = t & 15;
            #pragma unroll
            for (int p = 0; p < 4; p++) {
                int r = r0 + srow + 16 * p;
                float4 v = make_float4(0.f, 0.f, 0.f, 0.f);
                if (r < N) v = *(const float4*)(x + (size_t)r * 128 + kc + 4 * sf4);
                *(float4*)&xs[srow + 16 * p][4 * sf4] = v;
            }
            __syncthreads();
            #pragma unroll 4
            for (int k = 0; k < 64; k++) {
                float4 bv = *(float4*)&Bs[(kc + k) * 64 + 4 * ct];
                #pragma unroll
                for (int i = 0; i < 4; i++) {
                    float xv = xs[4 * rt + i][k];
                    acc[i][0] = fmaf(xv, bv.x, acc[i][0]);
                    acc[i][1] = fmaf(xv, bv.y, acc[i][1]);
                    acc[i][2] = fmaf(xv, bv.z, acc[i][2]);
                    acc[i][3] = fmaf(xv, bv.w, acc[i][3]);
                }
            }
        }
        #pragma unroll
        for (int i = 0; i < 4; i++) {
            int r = r0 + 4 * rt + i;
            float ps = 0.f, pd = 0.f;
            #pragma unroll
            for (int j = 0; j < 4; j++) {
                ps = fmaf(acc[i][j], asv[j], ps);
                pd = fmaf(acc[i][j], adv[j], pd);
            }
            ps += __shfl_xor(ps, 1); ps += __shfl_xor(ps, 2);
            pd += __shfl_xor(pd, 1); pd += __shfl_xor(pd, 2);
            if (r < N) {
                __half2 h0 = __floats2half2_rn(acc[i][0], acc[i][1]);
                __half2 h1 = __floats2half2_rn(acc[i][2], acc[i][3]);
                *(__half2*)(h + (size_t)r * 64 + 4 * ct) = h0;
                *(__half2*)(h + (size_t)r * 64 + 4 * ct + 2) = h1;
                if (cq == 0) { alsrc[r * 4 + head] = ps; aldst[r * 4 + head] = pd; }
            }
        }
    }
}

// ---------------- Layer 1 node aggregation: quarter-wave per node, 4-deep edge pipeline ----------------

__global__ __launch_bounds__(256) void node1_k(const __half* __restrict__ h, const int* __restrict__ srccol,
                                               const float* __restrict__ alsrc, const float* __restrict__ aldst,
                                               const int* __restrict__ rp, const int* __restrict__ cnt,
                                               const float* __restrict__ bias, __half* __restrict__ out, int N) {
    int t = threadIdx.x;
    int d = (blockIdx.x * 256 + t) >> 4;
    if (d >= N) return;
    int c = t & 15;
    int hc = c >> 2;
    const __half2* hb = (const __half2*)h;
    unsigned co = 2u * c;
    float ad = aldst[d * 4 + hc];
    float e = alsrc[d * 4 + hc] + ad;
    float w = __expf(e > 0.f ? e : NEG * e);
    float den = w;
    __half2 wp = __float2half2_rn(w);
    uint2 u = *(const uint2*)(hb + ((unsigned)d << 5) + co);
    __half2 acc0 = __hmul2(wp, *(__half2*)&u.x);
    __half2 acc1 = __hmul2(wp, *(__half2*)&u.y);
    int start = rp[d], deg = cnt[d];
    int i = 0;
    for (; i + 3 < deg; i += 4) {
        int s0 = srccol[start + i];
        int s1 = srccol[start + i + 1];
        int s2 = srccol[start + i + 2];
        int s3 = srccol[start + i + 3];
        uint2 u0 = *(const uint2*)(hb + ((unsigned)s0 << 5) + co);
        uint2 u1 = *(const uint2*)(hb + ((unsigned)s1 << 5) + co);
        uint2 u2 = *(const uint2*)(hb + ((unsigned)s2 << 5) + co);
        uint2 u3 = *(const uint2*)(hb + ((unsigned)s3 << 5) + co);
        float e0 = alsrc[s0 * 4 + hc] + ad;
        float e1 = alsrc[s1 * 4 + hc] + ad;
        float e2 = alsrc[s2 * 4 + hc] + ad;
        float e3 = alsrc[s3 * 4 + hc] + ad;
        float w0 = __expf(e0 > 0.f ? e0 : NEG * e0);
        float w1 = __expf(e1 > 0.f ? e1 : NEG * e1);
        float w2 = __expf(e2 > 0.f ? e2 : NEG * e2);
        float w3 = __expf(e3 > 0.f ? e3 : NEG * e3);
        den += (w0 + w1) + (w2 + w3);
        __half2 p0 = __float2half2_rn(w0), p1 = __float2half2_rn(w1);
        __half2 p2 = __float2half2_rn(w2), p3 = __float2half2_rn(w3);
        acc0 = __hfma2(p0, *(__half2*)&u0.x, acc0);
        acc1 = __hfma2(p0, *(__half2*)&u0.y, acc1);
        acc0 = __hfma2(p1, *(__half2*)&u1.x, acc0);
        acc1 = __hfma2(p1, *(__half2*)&u1.y, acc1);
        acc0 = __hfma2(p2, *(__half2*)&u2.x, acc0);
        acc1 = __hfma2(p2, *(__half2*)&u2.y, acc1);
        acc0 = __hfma2(p3, *(__half2*)&u3.x, acc0);
        acc1 = __hfma2(p3, *(__half2*)&u3.y, acc1);
    }
    for (; i < deg; i++) {
        int s = srccol[start + i];
        uint2 us = *(const uint2*)(hb + ((unsigned)s << 5) + co);
        float es = alsrc[s * 4 + hc] + ad;
        float ws = __expf(es > 0.f ? es : NEG * es);
        den += ws;
        __half2 wps = __float2half2_rn(ws);
        acc0 = __hfma2(wps, *(__half2*)&us.x, acc0);
        acc1 = __hfma2(wps, *(__half2*)&us.y, acc1);
    }
    float inv = 1.f / den;
    float2 f0 = __half22float2(acc0), f1 = __half22float2(acc1);
    float4 b = *(const float4*)(bias + 4 * c);
    __half2 o0 = __floats2half2_rn(f0.x * inv + b.x, f0.y * inv + b.y);
    __half2 o1 = __floats2half2_rn(f1.x * inv + b.z, f1.y * inv + b.w);
    uint2 o; o.x = *(unsigned*)&o0; o.y = *(unsigned*)&o1;
    *(uint2*)(out + (size_t)d * 64 + 4 * c) = o;
}

// ---------------- Layer 2 GEMM: h2 = h1o(fp16) @ W2 (fp16 out), register-tiled ----------------

__global__ __launch_bounds__(256) void gemm2_k(const __half* __restrict__ xh, const float* __restrict__ W,
                                               const float* __restrict__ a_src, const float* __restrict__ a_dst,
                                               __half* __restrict__ h, float* __restrict__ alsrc,
                                               float* __restrict__ aldst, int N) {
    __shared__ float Bs[64 * 128];
    __shared__ float xs[64][68];
    int t = threadIdx.x;
    for (int i = t; i < 64 * 128 / 4; i += 256)
        ((float4*)Bs)[i] = ((const float4*)W)[i];
    int ct = t & 15, rt = t >> 4;
    int hA = ct >> 3, cq = ct & 7;
    float asA[4], adA[4], asB[4], adB[4];
    #pragma unroll
    for (int j = 0; j < 4; j++) {
        asA[j] = a_src[hA * 32 + 4 * cq + j];
        adA[j] = a_dst[hA * 32 + 4 * cq + j];
        asB[j] = a_src[(2 + hA) * 32 + 4 * cq + j];
        adB[j] = a_dst[(2 + hA) * 32 + 4 * cq + j];
    }
    int ntiles = (N + 63) >> 6;
    for (int tile = blockIdx.x; tile < ntiles; tile += gridDim.x) {
        int r0 = tile << 6;
        float accA[4][4], accB[4][4];
        #pragma unroll
        for (int i = 0; i < 4; i++)
            #pragma unroll
            for (int j = 0; j < 4; j++) { accA[i][j] = 0.f; accB[i][j] = 0.f; }
        __syncthreads();
        int srow = t >> 3, su = t & 7;
        #pragma unroll
        for (int p = 0; p < 2; p++) {
            int r = r0 + srow + 32 * p;
            float2 g0 = make_float2(0.f, 0.f), g1 = g0, g2 = g0, g3 = g0;
            if (r < N) {
                uint4 u = *(const uint4*)(xh + (size_t)r * 64 + 8 * su);
                const __half2* hp = (const __half2*)&u;
                g0 = __half22float2(hp[0]); g1 = __half22float2(hp[1]);
                g2 = __half22float2(hp[2]); g3 = __half22float2(hp[3]);
            }
            *(float4*)&xs[srow + 32 * p][8 * su] = make_float4(g0.x, g0.y, g1.x, g1.y);
            *(float4*)&xs[srow + 32 * p][8 * su + 4] = make_float4(g2.x, g2.y, g3.x, g3.y);
        }
        __syncthreads();
        #pragma unroll 4
        for (int k = 0; k < 64; k++) {
            float4 bA = *(float4*)&Bs[k * 128 + 4 * ct];
            float4 bB = *(float4*)&Bs[k * 128 + 64 + 4 * ct];
            #pragma unroll
            for (int i = 0; i < 4; i++) {
                float xv = xs[4 * rt + i][k];
                accA[i][0] = fmaf(xv, bA.x, accA[i][0]);
                accA[i][1] = fmaf(xv, bA.y, accA[i][1]);
                accA[i][2] = fmaf(xv, bA.z, accA[i][2]);
                accA[i][3] = fmaf(xv, bA.w, accA[i][3]);
                accB[i][0] = fmaf(xv, bB.x, accB[i][0]);
                accB[i][1] = fmaf(xv, bB.y, accB[i][1]);
                accB[i][2] = fmaf(xv, bB.z, accB[i][2]);
                accB[i][3] = fmaf(xv, bB.w, accB[i][3]);
            }
        }
        #pragma unroll
        for (int i = 0; i < 4; i++) {
            int r = r0 + 4 * rt + i;
            float psA = 0.f, pdA = 0.f, psB = 0.f, pdB = 0.f;
            #pragma unroll
            for (int j = 0; j < 4; j++) {
                psA = fmaf(accA[i][j], asA[j], psA);
                pdA = fmaf(accA[i][j], adA[j], pdA);
                psB = fmaf(accB[i][j], asB[j], psB);
                pdB = fmaf(accB[i][j], adB[j], pdB);
            }
            #pragma unroll
            for (int off = 1; off <= 4; off <<= 1) {
                psA += __shfl_xor(psA, off); pdA += __shfl_xor(pdA, off);
                psB += __shfl_xor(psB, off); pdB += __shfl_xor(pdB, off);
            }
            if (r < N) {
                __half2 hA0 = __floats2half2_rn(accA[i][0], accA[i][1]);
                __half2 hA1 = __floats2half2_rn(accA[i][2], accA[i][3]);
                __half2 hB0 = __floats2half2_rn(accB[i][0], accB[i][1]);
                __half2 hB1 = __floats2half2_rn(accB[i][2], accB[i][3]);
                *(__half2*)(h + (size_t)r * 128 + 4 * ct) = hA0;
                *(__half2*)(h + (size_t)r * 128 + 4 * ct + 2) = hA1;
                *(__half2*)(h + (size_t)r * 128 + 64 + 4 * ct) = hB0;
                *(__half2*)(h + (size_t)r * 128 + 64 + 4 * ct + 2) = hB1;
                if (cq == 0) {
                    alsrc[r * 4 + hA] = psA;     alsrc[r * 4 + 2 + hA] = psB;
                    aldst[r * 4 + hA] = pdA;     aldst[r * 4 + 2 + hA] = pdB;
                }
            }
        }
    }
}

// ---------------- Layer 2 node aggregation: quarter-wave per node, 4-deep pipeline + epilogue ----------------

__global__ __launch_bounds__(256) void node2_k(const __half* __restrict__ h, const int* __restrict__ srccol,
                                               const float* __restrict__ alsrc, const float* __restrict__ aldst,
                                               const int* __restrict__ rp, const int* __restrict__ cnt,
                                               const float* __restrict__ bias, float* __restrict__ out, int N) {
    int t = threadIdx.x;
    int d = (blockIdx.x * 256 + t) >> 4;
    if (d >= N) return;
    int c = t & 15;
    int hc = c >> 2, jc = c & 3;
    const __half2* hb = (const __half2*)h;
    unsigned co = 4u * c;
    float ad = aldst[d * 4 + hc];
    float e = alsrc[d * 4 + hc] + ad;
    float w = __expf(e > 0.f ? e : NEG * e);
    float den = w;
    __half2 wp = __float2half2_rn(w);
    uint4 u = *(const uint4*)(hb + ((unsigned)d << 6) + co);
    const __half2* hp = (const __half2*)&u;
    __half2 acc[4];
    #pragma unroll
    for (int j = 0; j < 4; j++) acc[j] = __hmul2(wp, hp[j]);
    int start = rp[d], deg = cnt[d];
    int i = 0;
    for (; i + 3 < deg; i += 4) {
        int s0 = srccol[start + i];
        int s1 = srccol[start + i + 1];
        int s2 = srccol[start + i + 2];
        int s3 = srccol[start + i + 3];
        uint4 u0 = *(const uint4*)(hb + ((unsigned)s0 << 6) + co);
        uint4 u1 = *(const uint4*)(hb + ((unsigned)s1 << 6) + co);
        uint4 u2 = *(const uint4*)(hb + ((unsigned)s2 << 6) + co);
        uint4 u3 = *(const uint4*)(hb + ((unsigned)s3 << 6) + co);
        float e0 = alsrc[s0 * 4 + hc] + ad;
        float e1 = alsrc[s1 * 4 + hc] + ad;
        float e2 = alsrc[s2 * 4 + hc] + ad;
        float e3 = alsrc[s3 * 4 + hc] + ad;
        float w0 = __expf(e0 > 0.f ? e0 : NEG * e0);
        float w1 = __expf(e1 > 0.f ? e1 : NEG * e1);
        float w2 = __expf(e2 > 0.f ? e2 : NEG * e2);
        float w3 = __expf(e3 > 0.f ? e3 : NEG * e3);
        den += (w0 + w1) + (w2 + w3);
        __half2 p0 = __float2half2_rn(w0), p1 = __float2half2_rn(w1);
        __half2 p2 = __float2half2_rn(w2), p3 = __float2half2_rn(w3);
        const __half2* q0 = (const __half2*)&u0;
        const __half2* q1 = (const __half2*)&u1;
        const __half2* q2 = (const __half2*)&u2;
        const __half2* q3 = (const __half2*)&u3;
        #pragma unroll
        for (int j = 0; j < 4; j++) acc[j] = __hfma2(p0, q0[j], acc[j]);
        #pragma unroll
        for (int j = 0; j < 4; j++) acc[j] = __hfma2(p1, q1[j], acc[j]);
        #pragma unroll
        for (int j = 0; j < 4; j++) acc[j] = __hfma2(p2, q2[j], acc[j]);
        #pragma unroll
        for (int j = 0; j < 4; j++) acc[j] = __hfma2(p3, q3[j], acc[j]);
    }
    for (; i < deg; i++) {
        int s = srccol[start + i];
        uint4 us = *(const uint4*)(hb + ((unsigned)s << 6) + co);
        float es = alsrc[s * 4 + hc] + ad;
        float ws = __expf(es > 0.f ? es : NEG * es);
        den += ws;
        __half2 wps = __float2half2_rn(ws);
        const __half2* hps = (const __half2*)&us;
        #pragma unroll
        for (int j = 0; j < 4; j++) acc[j] = __hfma2(wps, hps[j], acc[j]);
    }
    float inv = 1.f / den;
    float v[8];
    #pragma unroll
    for (int j = 0; j < 4; j++) {
        float2 f = __half22float2(acc[j]);
        v[2 * j] = f.x * inv; v[2 * j + 1] = f.y * inv;
    }
    // head-mean: sum across lanes with same jc (lane bits 4 and 8)
    #pragma unroll
    for (int off = 4; off <= 8; off <<= 1) {
        #pragma unroll
        for (int j = 0; j < 8; j++) v[j] += __shfl_xor(v[j], off);
    }
    float ev[8];
    #pragma unroll
    for (int j = 0; j < 8; j++) {
        float val = 0.25f * v[j] + bias[8 * jc + j];
        ev[j] = val > 0.f ? val : __expf(val) - 1.f;
    }
    float mx = ev[0];
    #pragma unroll
    for (int j = 1; j < 8; j++) mx = fmaxf(mx, ev[j]);
    #pragma unroll
    for (int off = 1; off <= 2; off <<= 1) mx = fmaxf(mx, __shfl_xor(mx, off));
    float sum = 0.f;
    #pragma unroll
    for (int j = 0; j < 8; j++) sum += __expf(ev[j] - mx);
    #pragma unroll
    for (int off = 1; off <= 2; off <<= 1) sum += __shfl_xor(sum, off);
    float ls = mx + __logf(sum);
    if (c < 4) {
        float4 o0, o1;
        o0.x = ev[0] - ls; o0.y = ev[1] - ls; o0.z = ev[2] - ls; o0.w = ev[3] - ls;
        o1.x = ev[4] - ls; o1.y = ev[5] - ls; o1.z = ev[6] - ls; o1.w = ev[7] - ls;
        *(float4*)(out + (size_t)d * 32 + 8 * jc) = o0;
        *(float4*)(out + (size_t)d * 32 + 8 * jc + 4) = o1;
    }
}

// ---------------- launch ----------------

extern "C" void kernel_launch(void* const* d_in, const int* in_sizes, int n_in,
                              void* d_out, int out_size, void* d_ws, size_t ws_size,
                              hipStream_t stream) {
    const float* x   = (const float*)d_in[0];
    const int*   ei  = (const int*)d_in[1];
    const float* W1  = (const float*)d_in[2];
    const float* as1 = (const float*)d_in[3];
    const float* ad1 = (const float*)d_in[4];
    const float* b1  = (const float*)d_in[5];
    const float* W2  = (const float*)d_in[6];
    const float* as2 = (const float*)d_in[7];
    const float* ad2 = (const float*)d_in[8];
    const float* b2  = (const float*)d_in[9];
    float* out = (float*)d_out;
    int N = in_sizes[0] / 128;
    int E = in_sizes[1] / 2;

    char* base = (char*)d_ws;
    size_t off = 0;
    auto alloc = [&](size_t bytes) -> char* {
        char* p = base + off;
        off = (off + bytes + 255) & ~(size_t)255;
        return p;
    };
    __half* h1h   = (__half*)alloc((size_t)N * 64 * 2);
    __half* h1o   = (__half*)alloc((size_t)N * 64 * 2);
    __half* h2h   = (__half*)alloc((size_t)N * 128 * 2);
    float* alsrc1 = (float*)alloc((size_t)N * 4 * 4);
    float* aldst1 = (float*)alloc((size_t)N * 4 * 4);
    float* alsrc2 = (float*)alloc((size_t)N * 4 * 4);
    float* aldst2 = (float*)alloc((size_t)N * 4 * 4);
    int* cnt  = (int*)alloc((size_t)N * 4);
    int* rp   = (int*)alloc((size_t)N * 4);
    int* curA = (int*)alloc(256 * 4);
    int* bs   = (int*)alloc(1024 * 4);
    int* srccol = (int*)alloc((size_t)E * 4);
    uint2* pairs = (uint2*)alloc((size_t)E * 8);

    int nbk = (N + 511) >> 9;       // 512-node buckets
    int ntilesA = (E + TILE - 1) / TILE;
    int nb = (N + 255) / 256;

    hipMemsetAsync(cnt, 0, (size_t)N * 4, stream);
    hist_k<<<(E + 255) / 256, 256, 0, stream>>>(ei, cnt, E);
    scan1_k<<<nb, 256, 0, stream>>>(cnt, rp, bs, N);
    scan2_k<<<1, 1024, 0, stream>>>(bs, nb);
    scan3_k<<<nb, 256, 0, stream>>>(rp, bs, N);
    initA_k<<<1, 256, 0, stream>>>(rp, curA, nbk);
    partA_k<<<ntilesA, 256, 0, stream>>>(ei, curA, pairs, E, nbk);
    partB_pairs_k<<<nbk, 256, 0, stream>>>(pairs, rp, srccol, E, N);

    gemm1_k<<<768, 256, 0, stream>>>(x, W1, as1, ad1, h1h, alsrc1, aldst1, N);
    node1_k<<<(N + 15) / 16, 256, 0, stream>>>(h1h, srccol, alsrc1, aldst1, rp, cnt, b1, h1o, N);
    gemm2_k<<<768, 256, 0, stream>>>(h1o, W2, as2, ad2, h2h, alsrc2, aldst2, N);
    node2_k<<<(N + 15) / 16, 256, 0, stream>>>(h2h, srccol, alsrc2, aldst2, rp, cnt, b2, out, N);
}